// Round 11
// baseline (133.213 us; speedup 1.0000x reference)
//
#include <hip/hip_runtime.h>
#include <hip/hip_bf16.h>
#include <stdint.h>

#define K_DIM 1024
#define N_DIM 1024

typedef __attribute__((ext_vector_type(8))) short  short8;
typedef __attribute__((ext_vector_type(4))) float  f32x4;
typedef __attribute__((ext_vector_type(4))) unsigned int u32x4;

__device__ __forceinline__ ushort f2bf(float f) {
  union { float f; uint32_t u; } v; v.f = f;
  uint32_t r = v.u + 0x7FFFu + ((v.u >> 16) & 1u);
  return (ushort)(r >> 16);
}
__device__ __forceinline__ uint32_t pack_bf2(float a, float b) {
  __hip_bfloat162 h = __float22bfloat162_rn(make_float2(a, b));
  union { __hip_bfloat162 h; uint32_t u; } c; c.h = h;
  return c.u;
}

// ------- kernel 1: convert x -> bf16 (blocks 0..8191) + build T (8192..8703)
__global__ __launch_bounds__(256) void prep_kernel(
    const float* __restrict__ X, ushort* __restrict__ XB,
    const float* __restrict__ fr, const float* __restrict__ fc,
    ushort* __restrict__ T) {
  const int bid = blockIdx.x;
  if (bid < 8192) {
    size_t idx = ((size_t)bid * 256 + threadIdx.x) * 8;
    const size_t stride = (size_t)8192 * 256 * 8;
#pragma unroll
    for (int it = 0; it < 2; ++it) {
      f32x4 a = *reinterpret_cast<const f32x4*>(X + idx);
      f32x4 b = *reinterpret_cast<const f32x4*>(X + idx + 4);
      u32x4 p;
      p.x = pack_bf2(a.x, a.y); p.y = pack_bf2(a.z, a.w);
      p.z = pack_bf2(b.x, b.y); p.w = pack_bf2(b.z, b.w);
      *reinterpret_cast<u32x4*>(XB + idx) = p;
      idx += stride;
    }
  } else {
    int idx = (bid - 8192) * 256 + threadIdx.x;
    int o  = idx >> 7;
    int i0 = (idx & 127) << 3;
    short8 v;
#pragma unroll
    for (int j = 0; j < 8; ++j) {
      int d = o - (i0 + j);
      float f = (d >= 0) ? fc[d] : fr[-d];
      v[j] = (short)f2bf(f);
    }
    *reinterpret_cast<short8*>(T + (size_t)idx * 8) = v;
  }
}

// ---- kernel 2: 256x256 bf16; flat 2-barrier/tile; 256 blocks x 2 n-tiles ---
__global__ __launch_bounds__(512, 1) void gemm_flat(
    const ushort* __restrict__ XB, const ushort* __restrict__ T,
    const float* __restrict__ bias, float* __restrict__ Out) {
  // buf c at c*65536: A [256r][128B] @ +0, B @ +32768. 128 KiB total.
  __shared__ alignas(16) char smem[131072];

  const int tid  = threadIdx.x;
  const int lane = tid & 63;
  const int wv   = tid >> 6;
  const int wm   = wv >> 2, wn = wv & 3;      // 2x4 wave grid, 128x64 tiles
  const int cc   = lane & 15, kg = lane >> 4;

  // 256 blocks = 8 xcd * 32; sibling blocks (same m-panel) land on same XCD.
  const int swz = (blockIdx.x & 7) * 32 + (blockIdx.x >> 3);
  const int m0    = (swz >> 1) * 256;   // 128 m-panels
  const int npair = swz & 1;            // n-tiles npair*512 + {0,256}

  const int r0  = tid >> 3;
  const int kbs = (((tid & 7) * 16) ^ ((r0 & 7) << 4)) >> 1;  // pre-swizzled k
  const ushort* aSrc  = XB + (size_t)(m0 + r0) * K_DIM + kbs;
  const ushort* bSrc0 = T  + (size_t)(npair * 512 + r0) * K_DIM + kbs;
  const int dOff = tid * 16;

  const int kx0 = (kg * 16) ^ ((cc & 7) << 4);
  const int kx1 = (64 + kg * 16) ^ ((cc & 7) << 4);
  const int aRow = (wm * 128 + cc) * 128;          // + mf*2048
  const int bRow = 32768 + (wn * 64 + cc) * 128;   // + nf*2048

  short8 afr[8][2];   // 64 VGPR
  short8 bfr[4][2];   // 32 VGPR
  f32x4  acc[8][4];   // 128 acc

#define SB0() __builtin_amdgcn_sched_barrier(0)
#define BAR() __builtin_amdgcn_s_barrier()
#define GATE8 asm volatile("s_waitcnt vmcnt(8)" ::: "memory")
#define GATE0 asm volatile("s_waitcnt vmcnt(0)" ::: "memory")

#define RD(off) (*reinterpret_cast<const short8*>(smem + (off)))

#define READS(BUF)                                                          \
  { _Pragma("unroll")                                                       \
    for (int mf = 0; mf < 4; ++mf) {                                        \
      afr[mf][0] = RD((BUF) + aRow + mf * 2048 + kx0);                      \
      afr[mf][1] = RD((BUF) + aRow + mf * 2048 + kx1);                      \
    }                                                                       \
    _Pragma("unroll")                                                       \
    for (int nf = 0; nf < 4; ++nf) {                                        \
      bfr[nf][0] = RD((BUF) + bRow + nf * 2048 + kx0);                      \
      bfr[nf][1] = RD((BUF) + bRow + nf * 2048 + kx1);                      \
    }                                                                       \
    _Pragma("unroll")                                                       \
    for (int mf = 4; mf < 8; ++mf) {                                        \
      afr[mf][0] = RD((BUF) + aRow + mf * 2048 + kx0);                      \
      afr[mf][1] = RD((BUF) + aRow + mf * 2048 + kx1);                      \
    } }

#define STG_A(kt, BUF)                                                      \
  { _Pragma("unroll")                                                       \
    for (int h = 0; h < 2; ++h)                                             \
      _Pragma("unroll")                                                     \
      for (int s = 0; s < 2; ++s) {                                         \
        const ushort* src = aSrc + (size_t)(h * 128 + s * 64) * K_DIM + (kt) * 64; \
        char* dst = smem + (BUF) + h * 16384 + s * 8192 + dOff;             \
        __builtin_amdgcn_global_load_lds(                                   \
            (const __attribute__((address_space(1))) void*)src,             \
            (__attribute__((address_space(3))) void*)dst, 16, 0, 0);        \
      } }

#define STG_B(BS, kt, BUF)                                                  \
  { _Pragma("unroll")                                                       \
    for (int h = 0; h < 2; ++h)                                             \
      _Pragma("unroll")                                                     \
      for (int s = 0; s < 2; ++s) {                                         \
        const ushort* src = (BS) + (size_t)(h * 128 + s * 64) * K_DIM + (kt) * 64; \
        char* dst = smem + (BUF) + 32768 + h * 16384 + s * 8192 + dOff;     \
        __builtin_amdgcn_global_load_lds(                                   \
            (const __attribute__((address_space(1))) void*)src,             \
            (__attribute__((address_space(3))) void*)dst, 16, 0, 0);        \
      } }

#define MFMAQ(mfb, nfb)                                                     \
  { __builtin_amdgcn_s_setprio(1);                                         \
    _Pragma("unroll")                                                       \
    for (int mf = 0; mf < 4; ++mf)                                          \
      _Pragma("unroll")                                                     \
      for (int nf = 0; nf < 2; ++nf) {                                      \
        acc[(mfb) + mf][(nfb) + nf] = __builtin_amdgcn_mfma_f32_16x16x32_bf16( \
            afr[(mfb) + mf][0], bfr[(nfb) + nf][0],                         \
            acc[(mfb) + mf][(nfb) + nf], 0, 0, 0);                          \
        acc[(mfb) + mf][(nfb) + nf] = __builtin_amdgcn_mfma_f32_16x16x32_bf16( \
            afr[(mfb) + mf][1], bfr[(nfb) + nf][1],                         \
            acc[(mfb) + mf][(nfb) + nf], 0, 0, 0);                          \
      }                                                                     \
    __builtin_amdgcn_s_setprio(0); }

#pragma unroll 1
  for (int np = 0; np < 2; ++np) {
    const ushort* bS = bSrc0 + (size_t)np * 256 * K_DIM;

    // zero accumulators
#pragma unroll
    for (int mf = 0; mf < 8; ++mf)
#pragma unroll
      for (int nf = 0; nf < 4; ++nf)
        acc[mf][nf] = (f32x4){0.f, 0.f, 0.f, 0.f};

    if (np == 0) {
      // prologue: stage tiles 0 (buf0) and 1 (buf1); retire tile 0
      STG_A(0, 0);     SB0();
      STG_B(bS, 0, 0); SB0();
      STG_A(1, 65536); SB0();
      STG_B(bS, 1, 65536); SB0();
      GATE8;                       // tile0 landed; tile1's 8 in flight
      SB0(); BAR(); SB0();
    }
    // np==1: tiles 0,1 staged during np0's t15; drained by GATE0 + BAR there.

#pragma unroll 1
    for (int t = 0; t < 16; ++t) {
      const int cur = (t & 1) * 65536;
      if (t >= 1) {
        if (t == 15) { GATE0; } else { GATE8; }   // retire tile t's 8 DMAs
        SB0(); BAR(); SB0();
      }
      READS(cur);                                 // 24 x ds_read_b128
      SB0(); BAR(); SB0();                        // all waves done reading cur
      if (t < 14) {
        STG_A(t + 2, cur); SB0();
        STG_B(bS, t + 2, cur); SB0();
      } else if (t == 15 && np == 0) {
        // transition: stage n1 tiles 0,1 (post-BAR2 of t15 -> safe)
        const ushort* bS1 = bSrc0 + (size_t)256 * K_DIM;
        STG_A(0, 0);      SB0();
        STG_B(bS1, 0, 0); SB0();
        STG_A(1, 65536);  SB0();
        STG_B(bS1, 1, 65536); SB0();
      }
      MFMAQ(0, 0); MFMAQ(0, 2); MFMAQ(4, 2); MFMAQ(4, 0);
    }

    if (np == 0) {
      GATE0;                       // drain n1 tile-0/1 stages (L2-hot, cheap)
      SB0(); BAR(); SB0();
    }

    // epilogue: bias + fp32 store for this n-tile
    const int nbase = npair * 512 + np * 256;
#pragma unroll
    for (int nf = 0; nf < 4; ++nf) {
      const int col = nbase + wn * 64 + nf * 16 + cc;
      const float bv = bias[col];
#pragma unroll
      for (int mf = 0; mf < 8; ++mf) {
        const int row0 = m0 + wm * 128 + mf * 16 + kg * 4;
        float* op = Out + (size_t)row0 * N_DIM + col;
#pragma unroll
        for (int j = 0; j < 4; ++j)
          op[(size_t)j * N_DIM] = acc[mf][nf][j] + bv;
      }
    }
  }
#undef MFMAQ
#undef STG_A
#undef STG_B
#undef READS
#undef RD
#undef SB0
#undef BAR
#undef GATE8
#undef GATE0
}

// ---------------- fallback (ws too small): naive fp32 ----------------------
__global__ __launch_bounds__(256) void toeplitz_naive(
    const float* __restrict__ x, const float* __restrict__ fr,
    const float* __restrict__ fc, const float* __restrict__ bias,
    float* __restrict__ out) {
  __shared__ float sx[1024], sfr[1024], sfc[1024];
  const int m = blockIdx.x;
  for (int i = threadIdx.x; i < 1024; i += 256) {
    sx[i]  = x[(size_t)m * 1024 + i];
    sfr[i] = fr[i];
    sfc[i] = fc[i];
  }
  __syncthreads();
  for (int q = 0; q < 4; ++q) {
    const int o = threadIdx.x + q * 256;
    float acc = bias[o];
    for (int i = 0; i <= o; ++i)       acc += sx[i] * sfc[o - i];
    for (int i = o + 1; i < 1024; ++i) acc += sx[i] * sfr[i - o];
    out[(size_t)m * 1024 + o] = acc;
  }
}

extern "C" void kernel_launch(void* const* d_in, const int* in_sizes, int n_in,
                              void* d_out, int out_size, void* d_ws, size_t ws_size,
                              hipStream_t stream) {
  const float* x    = (const float*)d_in[0];
  const float* fr   = (const float*)d_in[1];
  const float* fc   = (const float*)d_in[2];
  const float* bias = (const float*)d_in[3];
  float* out = (float*)d_out;

  const size_t T_BYTES  = (size_t)2 * 1024 * 1024;
  const size_t XB_BYTES = (size_t)32768 * 1024 * 2;

  if (ws_size >= T_BYTES + XB_BYTES) {
    ushort* T  = (ushort*)d_ws;
    ushort* XB = (ushort*)((char*)d_ws + T_BYTES);
    prep_kernel<<<dim3(8704), dim3(256), 0, stream>>>(x, XB, fr, fc, T);
    gemm_flat<<<dim3(256), dim3(512), 0, stream>>>(XB, T, bias, out);
  } else {
    toeplitz_naive<<<dim3(32768), dim3(256), 0, stream>>>(x, fr, fc, bias, out);
  }
}